// Round 8
// baseline (5691.906 us; speedup 1.0000x reference)
//
#include <hip/hip_runtime.h>
#include <math.h>

#define TSTEPS 1024
#define BATCH  512
#define HID    64
#define VOC    29
#define SOS    27
#define MASK29 0x1FFFFFFFu

#define NBLOCKS  256
#define NTHREADS 512
#define WMAX     16
#define XCH      8     // x prefetch chunk length (steps)

__device__ __forceinline__ float frcp(float x){ return __builtin_amdgcn_rcpf(x); }
__device__ __forceinline__ float sigmf(float x){ return frcp(1.0f + __expf(-x)); }
__device__ __forceinline__ float tanhfast(float x){ return 1.0f - 2.0f*frcp(1.0f + __expf(2.0f*x)); }

// Fused seq2seq. Encoder rebuilt on the PROVEN decoder step skeleton:
//   pair p=tid&1 computes half of gate row gd=qd*64+md; halves combined via shfl_xor(1);
//   i/f/g/o gathered via shfl_xor(2/4/6); all 512 threads active; ONE barrier per step.
// Decoder phase: round-7 v3 protocol verbatim (frozen-mask windows, LDS checkpoints,
// tagged u64 single-phase rendezvous, damped window growth).
__global__ __attribute__((amdgpu_flat_work_group_size(NTHREADS,NTHREADS), amdgpu_waves_per_eu(2,2)))
void s2s_kernel(const float* __restrict__ x,
                const float* __restrict__ Wih0, const float* __restrict__ Whh0,
                const float* __restrict__ bih0, const float* __restrict__ bhh0,
                const float* __restrict__ Wih1, const float* __restrict__ Whh1,
                const float* __restrict__ bih1, const float* __restrict__ bhh1,
                const float* __restrict__ W1ih, const float* __restrict__ W1hh,
                const float* __restrict__ b1ih, const float* __restrict__ b1hh,
                const float* __restrict__ W2ih, const float* __restrict__ W2hh,
                const float* __restrict__ b2ih, const float* __restrict__ b2hh,
                const float* __restrict__ clsW, const float* __restrict__ clsb,
                float* __restrict__ out,
                unsigned long long* __restrict__ mseq)
{
  const int tid = threadIdx.x;
  const int blk = blockIdx.x;
  const int b0  = blk * 2;

  const int pd = tid & 1;              // half (low/high 32 of the dot)
  const int qd = (tid >> 1) & 3;       // gate quadrant (i,f,g,o)
  const int md = tid >> 3;             // hidden unit 0..63
  const int gd = qd*64 + md;           // gate row

  // ---------------- shared ----------------
  __shared__ __align__(16) float xs[2][XCH][2][32];          // chunked x staging (4 KB)
  __shared__ __align__(16) float eh0[2][2][HID], eh1[2][2][HID]; // enc h, parity-dbuf
  __shared__ __align__(16) float clsW_s[VOC][68];
  __shared__ __align__(16) float clsb_s[32];
  __shared__ __align__(16) float h1s[2][2][HID], h2s[2][2][HID];
  __shared__ __align__(16) float h1ck[WMAX][2][HID], c1ck[WMAX][2][HID];
  __shared__ __align__(16) float h2ck[WMAX][2][HID], c2ck[WMAX][2][HID];
  __shared__ unsigned u_lds[WMAX];

  // one-time classifier staging (latency hides under encoder)
  for (int i=tid;i<VOC*HID;i+=NTHREADS) clsW_s[i/HID][i%HID] = clsW[i];
  if (tid<VOC) clsb_s[tid]=clsb[tid];

  const int cbase = pd ? 15 : 0;
  const int cn    = pd ? 14 : 15;

  float c1r[2], c2r[2];   // decoder c-state (registers; layer-1 enc c hands off directly)

  // ================= ENCODER phase =================
  {
    float w0h[32], w1i[32], w1h[32], wx[15];
    #pragma unroll
    for (int k=0;k<32;k++){
      w0h[k]=Whh0[gd*HID+32*pd+k];
      w1i[k]=Wih1[gd*HID+32*pd+k];
      w1h[k]=Whh1[gd*HID+32*pd+k];
    }
    #pragma unroll
    for (int j=0;j<15;j++) wx[j] = (j<cn) ? Wih0[gd*VOC+cbase+j] : 0.f;
    const float bias0 = pd ? 0.f : (bih0[gd]+bhh0[gd]);
    const float bias1 = pd ? 0.f : (bih1[gd]+bhh1[gd]);

    float c0r[2]={0.f,0.f};
    c1r[0]=0.f; c1r[1]=0.f;

    if (tid<256){ ((float*)eh0)[tid]=0.f; ((float*)eh1)[tid]=0.f; }
    // zero whole xs (pad cols 29..31 must not be NaN: pd=1 half reads col 29 times 0)
    { float* xf=(float*)xs; for (int i=tid;i<2*XCH*2*32;i+=NTHREADS) xf[i]=0.f; }
    __syncthreads();

    // chunked x loaders: 464 threads cover XCH steps x 2 rows x 29 cols
    const bool ldr  = tid < 2*VOC*XCH;
    const int  toff = ldr ? tid/(2*VOC) : 0;
    const int  lrem = ldr ? tid%(2*VOC) : 0;
    const int  lrow = lrem/VOC, lcol = lrem%VOC;
    if (ldr) xs[0][toff][lrow][lcol] =
        x[(size_t)toff*BATCH*VOC + (size_t)(b0+lrow)*VOC + lcol];
    __syncthreads();

    int pb=0;
    float xv=0.f;
    for (int t=0;t<TSTEPS;t++){
      if (((t&(XCH-1))==0) && ldr){
        const int tl = t + XCH + toff;
        xv = (tl < TSTEPS)
           ? x[(size_t)tl*BATCH*VOC + (size_t)(b0+lrow)*VOC + lcol] : 0.f;
      }

      const int par=(t>>3)&1, sl=t&7;

      // ---- ph0: layer-0 gate + activation (fused, dec-style) ----
      float h0n[2];
      #pragma unroll
      for (int u=0;u<2;u++){
        float a0=bias0,a1=0.f,a2=0.f,a3=0.f;
        const float* xr = xs[par][sl][u];
        #pragma unroll
        for (int j=0;j<15;j++){
          float pxv = xr[cbase+j]*wx[j];
          if ((j&3)==0) a0+=pxv; else if ((j&3)==1) a1+=pxv;
          else if ((j&3)==2) a2+=pxv; else a3+=pxv;
        }
        const float4* h4=(const float4*)(&eh0[pb][u][32*pd]);
        #pragma unroll
        for (int c=0;c<8;c++){
          float4 qv=h4[c];
          a0=fmaf(qv.x,w0h[4*c+0],a0); a1=fmaf(qv.y,w0h[4*c+1],a1);
          a2=fmaf(qv.z,w0h[4*c+2],a2); a3=fmaf(qv.w,w0h[4*c+3],a3);
        }
        float v=(a0+a1)+(a2+a3);
        v += __shfl_xor(v,1);
        float x2=__shfl_xor(v,2), x4=__shfl_xor(v,4), x6=__shfl_xor(v,6);
        float ig = qd==0?v : qd==1?x2 : qd==2?x4 : x6;
        float fg = qd==1?v : qd==0?x2 : qd==3?x4 : x6;
        float gg = qd==2?v : qd==3?x2 : qd==0?x4 : x6;
        float og = qd==3?v : qd==2?x2 : qd==1?x4 : x6;
        float c = sigmf(fg)*c0r[u] + sigmf(ig)*tanhfast(gg);
        c0r[u]=c; h0n[u]=sigmf(og)*tanhfast(c);
      }
      if ((tid&7)==0){ eh0[pb^1][0][md]=h0n[0]; eh0[pb^1][1][md]=h0n[1]; }
      // commit next x chunk (written parity != parity being read; first read after B1)
      if (((t&(XCH-1))==(XCH-1)) && ldr)
        xs[((t>>3)+1)&1][toff][lrow][lcol] = xv;
      __syncthreads();   // B1 (the only barrier per step)

      // ---- ph1: layer-1 gate + activation ----
      float h1n[2];
      #pragma unroll
      for (int u=0;u<2;u++){
        float a0=bias1,a1=0.f,a2=0.f,a3=0.f;
        const float4* i4=(const float4*)(&eh0[pb^1][u][32*pd]);
        const float4* h4=(const float4*)(&eh1[pb][u][32*pd]);
        #pragma unroll
        for (int c=0;c<8;c++){
          float4 qv=i4[c], wv=h4[c];
          a0=fmaf(qv.x,w1i[4*c+0],a0); a1=fmaf(qv.y,w1i[4*c+1],a1);
          a2=fmaf(qv.z,w1i[4*c+2],a2); a3=fmaf(qv.w,w1i[4*c+3],a3);
          a0=fmaf(wv.x,w1h[4*c+0],a0); a1=fmaf(wv.y,w1h[4*c+1],a1);
          a2=fmaf(wv.z,w1h[4*c+2],a2); a3=fmaf(wv.w,w1h[4*c+3],a3);
        }
        float v=(a0+a1)+(a2+a3);
        v += __shfl_xor(v,1);
        float x2=__shfl_xor(v,2), x4=__shfl_xor(v,4), x6=__shfl_xor(v,6);
        float ig = qd==0?v : qd==1?x2 : qd==2?x4 : x6;
        float fg = qd==1?v : qd==0?x2 : qd==3?x4 : x6;
        float gg = qd==2?v : qd==3?x2 : qd==0?x4 : x6;
        float og = qd==3?v : qd==2?x2 : qd==1?x4 : x6;
        float c = sigmf(fg)*c1r[u] + sigmf(ig)*tanhfast(gg);
        c1r[u]=c; h1n[u]=sigmf(og)*tanhfast(c);
      }
      if ((tid&7)==0){ eh1[pb^1][0][md]=h1n[0]; eh1[pb^1][1][md]=h1n[1]; }
      pb ^= 1;
      // no trailing barrier: next-step hazards are covered by next B1 (see analysis)
    }
    __syncthreads();   // encoder done: eh1[pb] = final h1 (pb==0 after 1024 flips)

    // handoff: dec h1 init from eh1[0]; c1 stays in this thread's c1r registers
    if (tid<128){
      int u=tid>>6,k=tid&63;
      h1s[0][u][k]=eh1[0][u][k];
      h2s[0][u][k]=0.f;
    }
    c2r[0]=0.f; c2r[1]=0.f;
  }
  __syncthreads();

  // ================= DECODER phase (v3 protocol, round-7 verbatim) =================
  float w1h[32], w2i[32], w2h[32], wi1c[15];
  #pragma unroll
  for (int k=0;k<32;k++){
    w1h[k]=W1hh[gd*HID+32*pd+k];
    w2i[k]=W2ih[gd*HID+32*pd+k];
    w2h[k]=W2hh[gd*HID+32*pd+k];
  }
  #pragma unroll
  for (int j=0;j<15;j++) wi1c[j] = (j<cn) ? W1ih[gd*VOC+cbase+j] : 0.f;
  const float biasg = pd ? 0.f : (b1ih[gd]+b1hh[gd]);
  const float bias2 = pd ? 0.f : (b2ih[gd]+b2hh[gd]);

  unsigned F = 1u<<SOS;
  int f = 0;
  unsigned rnd = 0;
  int Wcur = 4, streak = 0;
  int pb = 0;

  while (f < TSTEPS){
    const int Wr = (TSTEPS - f < Wcur) ? (TSTEPS - f) : Wcur;
    const unsigned tag = rnd + 1u;
    unsigned long long* __restrict__ mrow = mseq + (size_t)(rnd&1u)*(WMAX*256);

    if (tid < Wr) u_lds[tid] = 0u;

    float it0 = biasg;
    #pragma unroll
    for (int jj=0;jj<15;jj++) it0 += ((F>>(cbase+jj))&1u) ? wi1c[jj] : 0.f;

    // ---- speculative window (frozen mask F) ----
    for (int j=0;j<Wr;j++){
      float h1n[2];
      #pragma unroll
      for (int u=0;u<2;u++){
        float a0=it0,a1=0.f,a2=0.f,a3=0.f;
        const float4* h4=(const float4*)(&h1s[pb][u][32*pd]);
        #pragma unroll
        for (int c=0;c<8;c++){
          float4 qv=h4[c];
          a0=fmaf(qv.x,w1h[4*c+0],a0); a1=fmaf(qv.y,w1h[4*c+1],a1);
          a2=fmaf(qv.z,w1h[4*c+2],a2); a3=fmaf(qv.w,w1h[4*c+3],a3);
        }
        float v=(a0+a1)+(a2+a3);
        v += __shfl_xor(v,1);
        float x2=__shfl_xor(v,2), x4=__shfl_xor(v,4), x6=__shfl_xor(v,6);
        float ig = qd==0?v : qd==1?x2 : qd==2?x4 : x6;
        float fg = qd==1?v : qd==0?x2 : qd==3?x4 : x6;
        float gg = qd==2?v : qd==3?x2 : qd==0?x4 : x6;
        float og = qd==3?v : qd==2?x2 : qd==1?x4 : x6;
        float c = sigmf(fg)*c1r[u] + sigmf(ig)*tanhfast(gg);
        c1r[u]=c; h1n[u]=sigmf(og)*tanhfast(c);
      }
      if ((tid&7)==0){
        h1s[pb^1][0][md]=h1n[0]; h1s[pb^1][1][md]=h1n[1];
        h1ck[j][0][md]=h1n[0];   h1ck[j][1][md]=h1n[1];
        c1ck[j][0][md]=c1r[0];   c1ck[j][1][md]=c1r[1];
      }
      __syncthreads();   // B1

      float h2n[2];
      #pragma unroll
      for (int u=0;u<2;u++){
        float a0=bias2,a1=0.f,a2=0.f,a3=0.f;
        const float4* i4=(const float4*)(&h1s[pb^1][u][32*pd]);
        const float4* h4=(const float4*)(&h2s[pb][u][32*pd]);
        #pragma unroll
        for (int c=0;c<8;c++){
          float4 qv=i4[c], wv=h4[c];
          a0=fmaf(qv.x,w2i[4*c+0],a0); a1=fmaf(qv.y,w2i[4*c+1],a1);
          a2=fmaf(qv.z,w2i[4*c+2],a2); a3=fmaf(qv.w,w2i[4*c+3],a3);
          a0=fmaf(wv.x,w2h[4*c+0],a0); a1=fmaf(wv.y,w2h[4*c+1],a1);
          a2=fmaf(wv.z,w2h[4*c+2],a2); a3=fmaf(wv.w,w2h[4*c+3],a3);
        }
        float v=(a0+a1)+(a2+a3);
        v += __shfl_xor(v,1);
        float x2=__shfl_xor(v,2), x4=__shfl_xor(v,4), x6=__shfl_xor(v,6);
        float ig = qd==0?v : qd==1?x2 : qd==2?x4 : x6;
        float fg = qd==1?v : qd==0?x2 : qd==3?x4 : x6;
        float gg = qd==2?v : qd==3?x2 : qd==0?x4 : x6;
        float og = qd==3?v : qd==2?x2 : qd==1?x4 : x6;
        float c = sigmf(fg)*c2r[u] + sigmf(ig)*tanhfast(gg);
        c2r[u]=c; h2n[u]=sigmf(og)*tanhfast(c);
      }
      if ((tid&7)==0){
        h2s[pb^1][0][md]=h2n[0]; h2s[pb^1][1][md]=h2n[1];
        h2ck[j][0][md]=h2n[0];   h2ck[j][1][md]=h2n[1];
        c2ck[j][0][md]=c2r[0];   c2ck[j][1][md]=c2r[1];
      }
      __syncthreads();   // B2

      if (tid<64){
        const int s = f + j;
        int row=tid>>5, v=tid&31;
        float pv = -INFINITY;
        if (v<VOC){
          float a0=clsb_s[v],a1=0.f,a2=0.f,a3=0.f;
          const float4* h4=(const float4*)h2s[pb^1][row];
          #pragma unroll
          for (int c=0;c<16;c++){
            float4 qv=h4[c];
            a0=fmaf(qv.x,clsW_s[v][4*c+0],a0); a1=fmaf(qv.y,clsW_s[v][4*c+1],a1);
            a2=fmaf(qv.z,clsW_s[v][4*c+2],a2); a3=fmaf(qv.w,clsW_s[v][4*c+3],a3);
          }
          pv=(a0+a1)+(a2+a3);
          out[((size_t)s*BATCH + (size_t)(b0+row))*VOC + v]=pv;
        }
        int ix=v;
        #pragma unroll
        for (int off=16; off>0; off>>=1){
          float ov=__shfl_xor(pv,off);
          int   oi=__shfl_xor(ix,off);
          if (ov>pv || (ov==pv && oi<ix)){ pv=ov; ix=oi; }
        }
        unsigned bit = 1u<<ix;
        unsigned mb  = bit | __shfl_xor(bit,32);
        if (tid==0)
          __hip_atomic_store(&mrow[j*256+blk],
                             ((unsigned long long)tag<<32) | (unsigned long long)mb,
                             __ATOMIC_RELAXED, __HIP_MEMORY_SCOPE_AGENT);
      }
      pb ^= 1;
    }

    // ---- single-phase tagged rendezvous ----
    for (int w=tid; w<Wr*256; w+=NTHREADS){
      const int jj = w>>8, bb = w&255;
      unsigned long long vv;
      do {
        vv = __hip_atomic_load(&mrow[jj*256+bb], __ATOMIC_RELAXED, __HIP_MEMORY_SCOPE_AGENT);
      } while ((unsigned)(vv>>32) != tag);
      unsigned um = (unsigned)vv & MASK29;
      um |= __shfl_xor(um,1);  um |= __shfl_xor(um,2);  um |= __shfl_xor(um,4);
      um |= __shfl_xor(um,8);  um |= __shfl_xor(um,16); um |= __shfl_xor(um,32);
      if ((tid&63)==0) atomicOr(&u_lds[jj], um);
    }
    __syncthreads();

    // ---- validate (identical integer decision in every block) ----
    int jstar = Wr;
    for (int jj=1;jj<Wr;jj++){ if (u_lds[jj-1]!=F){ jstar=jj; break; } }

    if (jstar==Wr){
      F = u_lds[Wr-1];
      f += Wr; rnd++;
      streak++;
      if (streak>=4 && Wcur<WMAX) Wcur*=2;
    } else {
      const int jm = jstar-1;
      c1r[0]=c1ck[jm][0][md]; c1r[1]=c1ck[jm][1][md];
      c2r[0]=c2ck[jm][0][md]; c2r[1]=c2ck[jm][1][md];
      if (tid<128){
        int u=tid>>6,k=tid&63;
        h1s[0][u][k]=h1ck[jm][u][k];
        h2s[0][u][k]=h2ck[jm][u][k];
      }
      pb = 0;
      F = u_lds[jm]; f += jstar; rnd++;
      streak = 0; Wcur = jstar;
    }
    __syncthreads();
  }
}

extern "C" void kernel_launch(void* const* d_in, const int* in_sizes, int n_in,
                              void* d_out, int out_size, void* d_ws, size_t ws_size,
                              hipStream_t stream)
{
  const float* x     = (const float*)d_in[0];
  const float* eWih0 = (const float*)d_in[1];
  const float* eWhh0 = (const float*)d_in[2];
  const float* ebih0 = (const float*)d_in[3];
  const float* ebhh0 = (const float*)d_in[4];
  const float* eWih1 = (const float*)d_in[5];
  const float* eWhh1 = (const float*)d_in[6];
  const float* ebih1 = (const float*)d_in[7];
  const float* ebhh1 = (const float*)d_in[8];
  const float* d1Wih = (const float*)d_in[9];
  const float* d1Whh = (const float*)d_in[10];
  const float* d1bih = (const float*)d_in[11];
  const float* d1bhh = (const float*)d_in[12];
  const float* d2Wih = (const float*)d_in[13];
  const float* d2Whh = (const float*)d_in[14];
  const float* d2bih = (const float*)d_in[15];
  const float* d2bhh = (const float*)d_in[16];
  const float* clsW  = (const float*)d_in[17];
  const float* clsb  = (const float*)d_in[18];
  float* out = (float*)d_out;

  unsigned long long* mseq = (unsigned long long*)d_ws;
  hipMemsetAsync(mseq, 0, (size_t)2*WMAX*256*sizeof(unsigned long long), stream);

  void* args[] = { (void*)&x,
                   (void*)&eWih0,(void*)&eWhh0,(void*)&ebih0,(void*)&ebhh0,
                   (void*)&eWih1,(void*)&eWhh1,(void*)&ebih1,(void*)&ebhh1,
                   (void*)&d1Wih,(void*)&d1Whh,(void*)&d1bih,(void*)&d1bhh,
                   (void*)&d2Wih,(void*)&d2Whh,(void*)&d2bih,(void*)&d2bhh,
                   (void*)&clsW,(void*)&clsb,(void*)&out,(void*)&mseq };
  hipLaunchCooperativeKernel((void*)s2s_kernel, dim3(NBLOCKS), dim3(NTHREADS),
                             args, 0, stream);
}